// Round 2
// baseline (8978.199 us; speedup 1.0000x reference)
//
#include <hip/hip_runtime.h>
#include <hip/hip_bf16.h>

// Problem constants
#define NB 4
#define CDIM 192
#define HEADS 8
#define CP 24
#define HH 128
#define WW 128
#define NPIX 16384  // 128*128

typedef __hip_bfloat16 bf16;

__device__ __forceinline__ float toF(float v) { return v; }
__device__ __forceinline__ float toF(bf16 v) { return __bfloat162float(v); }
__device__ __forceinline__ void stF(float* p, float v) { *p = v; }
__device__ __forceinline__ void stF(bf16* p, float v) { *p = __float2bfloat16(v); }

// ---------------------------------------------------------------------------
// Generic 1x1-conv / per-pixel GEMM:
// out[b, oc, n] = bias[oc] + sum_ic W[oc, ic] * in(ch)[b, n]
// channel ch < ic_split comes from in0, else from in1 at (ch - ic_split).
// Block: 256 thr = 4 waves; 64 pixels x 32 ocs (8 per wave, wave-uniform oc).
// ---------------------------------------------------------------------------
template <typename TI, typename TO>
__global__ __launch_bounds__(256) void gemm1x1_kernel(
    const TI* __restrict__ in0, long long bs0,
    const TI* __restrict__ in1, long long bs1, int ic_split,
    int IC, const float* __restrict__ Wm, long long w_bstride,
    const float* __restrict__ bias,
    TO* __restrict__ out, long long bs_out)
{
    __shared__ float xs[192][64];
    int tid = threadIdx.x;
    int lane = tid & 63;
    int wave = tid >> 6;
    int b = blockIdx.z;
    int nb = blockIdx.x * 64;
    int ocb = blockIdx.y * 32 + wave * 8;

    const float* Wb = Wm + (long long)b * w_bstride;

    float acc[8];
#pragma unroll
    for (int j = 0; j < 8; ++j) acc[j] = bias[ocb + j];

    for (int icb = 0; icb < IC; icb += 192) {
        int icch = (IC - icb) < 192 ? (IC - icb) : 192;
        __syncthreads();
        for (int idx = tid; idx < icch * 64; idx += 256) {
            int ic = idx >> 6;
            int px = idx & 63;
            int ch = icb + ic;
            float v;
            if (ch < ic_split)
                v = toF(in0[(long long)b * bs0 + (long long)ch * NPIX + nb + px]);
            else
                v = toF(in1[(long long)b * bs1 + (long long)(ch - ic_split) * NPIX + nb + px]);
            xs[ic][px] = v;
        }
        __syncthreads();
        const float* wrow = Wb + (long long)ocb * IC + icb;
#pragma unroll 4
        for (int ic = 0; ic < icch; ++ic) {
            float xv = xs[ic][lane];
#pragma unroll
            for (int j = 0; j < 8; ++j)
                acc[j] = fmaf(wrow[(long long)j * IC + ic], xv, acc[j]);
        }
    }
#pragma unroll
    for (int j = 0; j < 8; ++j)
        stF(&out[(long long)b * bs_out + (long long)(ocb + j) * NPIX + nb + lane], acc[j]);
}

// ---------------------------------------------------------------------------
// Grouped / depthwise 3x3 conv, pad 1. GIN in-ch / GOUT out-ch per group.
// Block: 128 thr = one image row; 4 output rows per block, one group.
// bf16 in/out, fp32 compute.
// ---------------------------------------------------------------------------
template <int GIN, int GOUT>
__global__ __launch_bounds__(128) void dwconv3x3_kernel(
    const bf16* __restrict__ in, const float* __restrict__ Wm,
    const float* __restrict__ bias, bf16* __restrict__ out, int groups)
{
    __shared__ float xs[GIN][6][130];
    int x = threadIdx.x;
    int g = blockIdx.y;
    int b = blockIdx.z;
    int y0 = blockIdx.x * 4;
    long long bsin = (long long)groups * GIN * NPIX;
    long long bsout = (long long)groups * GOUT * NPIX;

#pragma unroll
    for (int ic = 0; ic < GIN; ++ic) {
        for (int r = 0; r < 6; ++r) {
            int yy = y0 + r - 1;
            float v = 0.f;
            if (yy >= 0 && yy < HH)
                v = toF(in[(long long)b * bsin + (long long)(g * GIN + ic) * NPIX + yy * WW + x]);
            xs[ic][r][x + 1] = v;
            if (x == 0) { xs[ic][r][0] = 0.f; xs[ic][r][129] = 0.f; }
        }
    }
    __syncthreads();

    for (int j = 0; j < GOUT; ++j) {
        int oc = g * GOUT + j;
        const float* wp = Wm + (long long)oc * GIN * 9;
        float bj = bias[oc];
        for (int ry = 0; ry < 4; ++ry) {
            float acc = bj;
#pragma unroll
            for (int ic = 0; ic < GIN; ++ic)
#pragma unroll
                for (int ky = 0; ky < 3; ++ky)
#pragma unroll
                    for (int kx = 0; kx < 3; ++kx)
                        acc = fmaf(wp[ic * 9 + ky * 3 + kx], xs[ic][ry + ky][x + kx], acc);
            stF(&out[(long long)b * bsout + (long long)oc * NPIX + (y0 + ry) * WW + x], acc);
        }
    }
}

// ---------------------------------------------------------------------------
// Dense 3x3 conv 192 -> 384, pad 1 (FLOP-heavy kv conv). fp32 in, bf16 out.
// Block: 256 thr = 4 waves; 64 pixels of one row x 32 ocs (8 per wave).
// Input staged in 2 ic-chunks of 96: [96][3 rows][66 cols].
// ---------------------------------------------------------------------------
__global__ __launch_bounds__(256) void conv3x3_kernel(
    const float* __restrict__ in, const float* __restrict__ Wm,
    const float* __restrict__ bias, bf16* __restrict__ out)
{
    __shared__ float xs[96][3][66];
    int tid = threadIdx.x;
    int lane = tid & 63;
    int wave = tid >> 6;
    int gx = blockIdx.x;
    int y = gx >> 1;
    int xstart = (gx & 1) * 64;
    int ocb = blockIdx.y * 32 + wave * 8;
    int b = blockIdx.z;

    float acc[8];
#pragma unroll
    for (int j = 0; j < 8; ++j) acc[j] = bias[ocb + j];

    for (int icb = 0; icb < 192; icb += 96) {
        __syncthreads();
        for (int idx = tid; idx < 96 * 3 * 66; idx += 256) {
            int col = idx % 66;
            int rest = idx / 66;
            int ky = rest % 3;
            int ic = rest / 3;
            int gxx = xstart + col - 1;
            int yy = y + ky - 1;
            float v = 0.f;
            if (gxx >= 0 && gxx < WW && yy >= 0 && yy < HH)
                v = in[((long long)b * CDIM + icb + ic) * NPIX + yy * WW + gxx];
            xs[ic][ky][col] = v;
        }
        __syncthreads();
#pragma unroll 2
        for (int ic = 0; ic < 96; ++ic) {
            float xv[3][3];
#pragma unroll
            for (int ky = 0; ky < 3; ++ky)
#pragma unroll
                for (int kx = 0; kx < 3; ++kx)
                    xv[ky][kx] = xs[ic][ky][lane + kx];
            const float* wp = Wm + ((long long)ocb * CDIM + icb + ic) * 9;
#pragma unroll
            for (int j = 0; j < 8; ++j) {
                const float* wj = wp + (long long)j * CDIM * 9;
#pragma unroll
                for (int ky = 0; ky < 3; ++ky)
#pragma unroll
                    for (int kx = 0; kx < 3; ++kx)
                        acc[j] = fmaf(wj[ky * 3 + kx], xv[ky][kx], acc[j]);
            }
        }
    }
#pragma unroll
    for (int j = 0; j < 8; ++j)
        stF(&out[((long long)b * 384 + ocb + j) * NPIX + y * WW + xstart + lane], acc[j]);
}

// ---------------------------------------------------------------------------
// Reductions: per-channel sum-of-squares for q,k,v and the 24x24 Gram
// G[b,h,cq,ck] = sum_n q[cq,n]*k[ck,n]. Atomic accumulation, grid (B*H, 64).
// ---------------------------------------------------------------------------
__global__ __launch_bounds__(256) void reduce_qkv_kernel(
    const bf16* __restrict__ q, long long bsq,
    const bf16* __restrict__ k, long long bsk,
    const bf16* __restrict__ v, long long bsv,
    float* __restrict__ ssq, float* __restrict__ gram)
{
    __shared__ float qs[24][129], ks[24][129], vs[24][129];
    int bh = blockIdx.x;
    int b = bh >> 3, h = bh & 7;
    int n0 = blockIdx.y * 256;
    int tid = threadIdx.x;

    float ag0 = 0.f, ag1 = 0.f, ag2 = 0.f;
    float accs = 0.f;
    int e0 = tid, e1 = tid + 256, e2 = tid + 512;

    for (int cc = 0; cc < 2; ++cc) {
        int nb = n0 + cc * 128;
        __syncthreads();
        for (int idx = tid; idx < 24 * 128; idx += 256) {
            int c = idx >> 7, i = idx & 127;
            long long off = (long long)(h * CP + c) * NPIX + nb + i;
            qs[c][i] = toF(q[(long long)b * bsq + off]);
            ks[c][i] = toF(k[(long long)b * bsk + off]);
            vs[c][i] = toF(v[(long long)b * bsv + off]);
        }
        __syncthreads();
        {
            int cq = e0 / 24, ck = e0 % 24;
            for (int i = 0; i < 128; ++i) ag0 = fmaf(qs[cq][i], ks[ck][i], ag0);
        }
        {
            int cq = e1 / 24, ck = e1 % 24;
            for (int i = 0; i < 128; ++i) ag1 = fmaf(qs[cq][i], ks[ck][i], ag1);
        }
        if (tid < 64) {
            int cq = e2 / 24, ck = e2 % 24;
            for (int i = 0; i < 128; ++i) ag2 = fmaf(qs[cq][i], ks[ck][i], ag2);
        }
        if (tid < 72) {
            int tensor = tid / 24, c = tid % 24;
            const float (*src)[129] = (tensor == 0) ? qs : (tensor == 1) ? ks : vs;
            for (int i = 0; i < 128; ++i) accs = fmaf(src[c][i], src[c][i], accs);
        }
    }
    float* gb = gram + (long long)bh * 576;
    atomicAdd(&gb[e0], ag0);
    atomicAdd(&gb[e1], ag1);
    if (tid < 64) atomicAdd(&gb[e2], ag2);
    if (tid < 72) {
        int tensor = tid / 24, c = tid % 24;
        atomicAdd(&ssq[tensor * (NB * CDIM) + b * CDIM + h * CP + c], accs);
    }
}

// ---------------------------------------------------------------------------
// Softmax + fold norms + proj into per-batch M (192x192). grid(B), block 256.
// ---------------------------------------------------------------------------
__global__ __launch_bounds__(256) void build_M_kernel(
    const float* __restrict__ ssq, const float* __restrict__ gram,
    const float* __restrict__ temp, const float* __restrict__ proj_w,
    float* __restrict__ M)
{
    __shared__ float A[HEADS][CP][CP];
    __shared__ float nq[CDIM], nk[CDIM], nv[CDIM];
    int b = blockIdx.x;
    int tid = threadIdx.x;
    if (tid < CDIM) {
        nq[tid] = fmaxf(sqrtf(ssq[0 * (NB * CDIM) + b * CDIM + tid]), 1e-12f);
        nk[tid] = fmaxf(sqrtf(ssq[1 * (NB * CDIM) + b * CDIM + tid]), 1e-12f);
        nv[tid] = fmaxf(sqrtf(ssq[2 * (NB * CDIM) + b * CDIM + tid]), 1e-12f);
    }
    __syncthreads();
    if (tid < CDIM) {
        int h = tid / CP, cq = tid % CP;
        float t = temp[h];
        float row[CP];
        float m = -1e30f;
#pragma unroll
        for (int ck = 0; ck < CP; ++ck) {
            float g = gram[(long long)b * (HEADS * 576) + h * 576 + cq * CP + ck];
            g = g / (nq[h * CP + cq] * nk[h * CP + ck]) * t;
            row[ck] = g;
            m = fmaxf(m, g);
        }
        float s = 0.f;
#pragma unroll
        for (int ck = 0; ck < CP; ++ck) { row[ck] = __expf(row[ck] - m); s += row[ck]; }
        float inv = 1.f / s;
#pragma unroll
        for (int ck = 0; ck < CP; ++ck)
            A[h][cq][ck] = row[ck] * inv / nv[h * CP + ck];
    }
    __syncthreads();
    for (int e = tid; e < CDIM * CDIM; e += 256) {
        int oc = e / CDIM, d = e % CDIM;
        int h2 = d / CP, ck = d % CP;
        float acc = 0.f;
#pragma unroll
        for (int cq = 0; cq < CP; ++cq)
            acc = fmaf(proj_w[(long long)oc * CDIM + h2 * CP + cq], A[h2][cq][ck], acc);
        M[(long long)b * (CDIM * CDIM) + e] = acc;
    }
}

__global__ void zero_kernel(float* __restrict__ p, int n)
{
    for (int i = blockIdx.x * 256 + threadIdx.x; i < n; i += gridDim.x * 256) p[i] = 0.f;
}

// ---------------------------------------------------------------------------
// Workspace layout (bytes), total ~202 MB:
//   A:  bf16[37,748,736]  [0          : 75,497,472)   qkv1 -> kv1 -> k_new/v_new
//   B:  bf16[37,748,736]  [75,497,472 : 150,994,944)  qkv (post grouped conv)
//   C:  bf16[25,165,824]  [150,994,944: 201,326,592)  kv2 (post depthwise)
//   stats: float          [201,326,592: ...)          ssq | gram | M
// ---------------------------------------------------------------------------
extern "C" void kernel_launch(void* const* d_in, const int* in_sizes, int n_in,
                              void* d_out, int out_size, void* d_ws, size_t ws_size,
                              hipStream_t stream)
{
    const float* x      = (const float*)d_in[0];
    const float* x_mask = (const float*)d_in[1];
    const float* temp   = (const float*)d_in[2];
    const float* q_w    = (const float*)d_in[3];
    const float* q_b    = (const float*)d_in[4];
    const float* qdw_w  = (const float*)d_in[5];
    const float* qdw_b  = (const float*)d_in[6];
    const float* kv_w   = (const float*)d_in[7];
    const float* kv_b   = (const float*)d_in[8];
    const float* kvdw_w = (const float*)d_in[9];
    const float* kvdw_b = (const float*)d_in[10];
    const float* newk_w = (const float*)d_in[11];
    const float* newk_b = (const float*)d_in[12];
    const float* newv_w = (const float*)d_in[13];
    const float* newv_b = (const float*)d_in[14];
    const float* proj_w = (const float*)d_in[15];
    const float* proj_b = (const float*)d_in[16];

    char* wsb = (char*)d_ws;
    bf16* A = (bf16*)wsb;                              // 37,748,736 elems
    bf16* Bq = (bf16*)(wsb + 75497472);                // 37,748,736 elems
    bf16* C = (bf16*)(wsb + 150994944);                // 25,165,824 elems
    float* stats = (float*)(wsb + 201326592);
    float* ssq  = stats;                               // 2304
    float* gram = ssq + 2304;                          // 18432
    float* Mbuf = gram + 18432;                        // 147456

    const long long N = NPIX;
    float* out = (float*)d_out;

    // zero the atomic-accumulated stats
    zero_kernel<<<16, 256, 0, stream>>>(ssq, 2304 + 18432);

    // S1: qkv1 = conv1x1(x, q_w) : 192 -> 576  (fp32 in, bf16 out) -> A
    gemm1x1_kernel<float, bf16><<<dim3(256, 18, 4), 256, 0, stream>>>(
        x, 192 * N, (const float*)nullptr, 0, 192, 192, q_w, 0, q_b, A, 576 * N);

    // S2: qkv = grouped 3x3 (groups=192, 3in/3out) -> B
    dwconv3x3_kernel<3, 3><<<dim3(32, 192, 4), 128, 0, stream>>>(
        A, qdw_w, qdw_b, Bq, 192);

    // S3: kv1 = dense conv3x3(x_mask) : 192 -> 384 (fp32 in, bf16 out) -> A (reuse)
    conv3x3_kernel<<<dim3(256, 12, 4), 256, 0, stream>>>(x_mask, kv_w, kv_b, A);

    // S4: kv2 = depthwise 3x3 (384 groups) -> C
    dwconv3x3_kernel<1, 1><<<dim3(32, 384, 4), 128, 0, stream>>>(
        A, kvdw_w, kvdw_b, C, 384);

    // S5: k_new = conv1x1([k ; k_mask], newk_w); v_new likewise -> A (reuse)
    bf16* k_new = A;
    bf16* v_new = A + 12582912;
    gemm1x1_kernel<bf16, bf16><<<dim3(256, 6, 4), 256, 0, stream>>>(
        Bq + 192 * N, 576 * N, C, 384 * N, 192, 384, newk_w, 0, newk_b,
        k_new, 192 * N);
    gemm1x1_kernel<bf16, bf16><<<dim3(256, 6, 4), 256, 0, stream>>>(
        Bq + 384 * N, 576 * N, C + 192 * N, 384 * N, 192, 384, newv_w, 0, newv_b,
        v_new, 192 * N);

    // S6: sumsq(q,k,v) + Gram(q,k)
    reduce_qkv_kernel<<<dim3(32, 64), 256, 0, stream>>>(
        Bq, 576 * N, k_new, 192 * N, v_new, 192 * N, ssq, gram);

    // S7: softmax + fold v-norm + proj -> per-batch M (192x192)
    build_M_kernel<<<4, 256, 0, stream>>>(ssq, gram, temp, proj_w, Mbuf);

    // S8: out = M_b @ v_new + proj_b  (bf16 in, fp32 out)
    gemm1x1_kernel<bf16, float><<<dim3(256, 6, 4), 256, 0, stream>>>(
        v_new, 192 * N, (const bf16*)nullptr, 0, 192, 192, Mbuf,
        (long long)CDIM * CDIM, proj_b, out, 192 * N);
}

// Round 3
// 2790.527 us; speedup vs baseline: 3.2174x; 3.2174x over previous
//
#include <hip/hip_runtime.h>
#include <hip/hip_bf16.h>

// Problem constants
#define NB 4
#define CDIM 192
#define HEADS 8
#define CP 24
#define HH 128
#define WW 128
#define NPIX 16384  // 128*128

typedef __hip_bfloat16 bf16;
typedef __bf16 bf16x8 __attribute__((ext_vector_type(8)));
typedef float f32x4 __attribute__((ext_vector_type(4)));

__device__ __forceinline__ float toF(float v) { return v; }
__device__ __forceinline__ float toF(bf16 v) { return __bfloat162float(v); }
__device__ __forceinline__ void stF(float* p, float v) { *p = v; }
__device__ __forceinline__ void stF(bf16* p, float v) { *p = __float2bfloat16(v); }
__device__ __forceinline__ unsigned short bfbits(float v) {
    bf16 h = __float2bfloat16(v);
    return *reinterpret_cast<unsigned short*>(&h);
}

// ---------------------------------------------------------------------------
// Generic 1x1-conv / per-pixel GEMM (fp32 FMA path, unchanged this round).
// ---------------------------------------------------------------------------
template <typename TI, typename TO>
__global__ __launch_bounds__(256) void gemm1x1_kernel(
    const TI* __restrict__ in0, long long bs0,
    const TI* __restrict__ in1, long long bs1, int ic_split,
    int IC, const float* __restrict__ Wm, long long w_bstride,
    const float* __restrict__ bias,
    TO* __restrict__ out, long long bs_out)
{
    __shared__ float xs[192][64];
    int tid = threadIdx.x;
    int lane = tid & 63;
    int wave = tid >> 6;
    int b = blockIdx.z;
    int nb = blockIdx.x * 64;
    int ocb = blockIdx.y * 32 + wave * 8;

    const float* Wb = Wm + (long long)b * w_bstride;

    float acc[8];
#pragma unroll
    for (int j = 0; j < 8; ++j) acc[j] = bias[ocb + j];

    for (int icb = 0; icb < IC; icb += 192) {
        int icch = (IC - icb) < 192 ? (IC - icb) : 192;
        __syncthreads();
        for (int idx = tid; idx < icch * 64; idx += 256) {
            int ic = idx >> 6;
            int px = idx & 63;
            int ch = icb + ic;
            float v;
            if (ch < ic_split)
                v = toF(in0[(long long)b * bs0 + (long long)ch * NPIX + nb + px]);
            else
                v = toF(in1[(long long)b * bs1 + (long long)(ch - ic_split) * NPIX + nb + px]);
            xs[ic][px] = v;
        }
        __syncthreads();
        const float* wrow = Wb + (long long)ocb * IC + icb;
#pragma unroll 4
        for (int ic = 0; ic < icch; ++ic) {
            float xv = xs[ic][lane];
#pragma unroll
            for (int j = 0; j < 8; ++j)
                acc[j] = fmaf(wrow[(long long)j * IC + ic], xv, acc[j]);
        }
    }
#pragma unroll
    for (int j = 0; j < 8; ++j)
        stF(&out[(long long)b * bs_out + (long long)(ocb + j) * NPIX + nb + lane], acc[j]);
}

// ---------------------------------------------------------------------------
// Grouped / depthwise 3x3 conv, pad 1 (unchanged).
// ---------------------------------------------------------------------------
template <int GIN, int GOUT>
__global__ __launch_bounds__(128) void dwconv3x3_kernel(
    const bf16* __restrict__ in, const float* __restrict__ Wm,
    const float* __restrict__ bias, bf16* __restrict__ out, int groups)
{
    __shared__ float xs[GIN][6][130];
    int x = threadIdx.x;
    int g = blockIdx.y;
    int b = blockIdx.z;
    int y0 = blockIdx.x * 4;
    long long bsin = (long long)groups * GIN * NPIX;
    long long bsout = (long long)groups * GOUT * NPIX;

#pragma unroll
    for (int ic = 0; ic < GIN; ++ic) {
        for (int r = 0; r < 6; ++r) {
            int yy = y0 + r - 1;
            float v = 0.f;
            if (yy >= 0 && yy < HH)
                v = toF(in[(long long)b * bsin + (long long)(g * GIN + ic) * NPIX + yy * WW + x]);
            xs[ic][r][x + 1] = v;
            if (x == 0) { xs[ic][r][0] = 0.f; xs[ic][r][129] = 0.f; }
        }
    }
    __syncthreads();

    for (int j = 0; j < GOUT; ++j) {
        int oc = g * GOUT + j;
        const float* wp = Wm + (long long)oc * GIN * 9;
        float bj = bias[oc];
        for (int ry = 0; ry < 4; ++ry) {
            float acc = bj;
#pragma unroll
            for (int ic = 0; ic < GIN; ++ic)
#pragma unroll
                for (int ky = 0; ky < 3; ++ky)
#pragma unroll
                    for (int kx = 0; kx < 3; ++kx)
                        acc = fmaf(wp[ic * 9 + ky * 3 + kx], xs[ic][ry + ky][x + kx], acc);
            stF(&out[(long long)b * bsout + (long long)oc * NPIX + (y0 + ry) * WW + x], acc);
        }
    }
}

// ---------------------------------------------------------------------------
// NCHW fp32 -> NHWC bf16 transpose-convert (for the MFMA conv's B operand).
// grid (256, 1, 4): blockIdx.x = y*2 + xhalf; tile [192 ic][64 px].
// ---------------------------------------------------------------------------
__global__ __launch_bounds__(256) void nchw2nhwc_kernel(
    const float* __restrict__ in, unsigned short* __restrict__ outp)
{
    __shared__ float xs[192][65];
    int tid = threadIdx.x;
    int y = blockIdx.x >> 1;
    int x0 = (blockIdx.x & 1) * 64;
    int b = blockIdx.z;

    for (int idx = tid; idx < 192 * 64; idx += 256) {
        int ic = idx >> 6, px = idx & 63;
        xs[ic][px] = in[(((long long)b * CDIM + ic) << 14) + y * WW + x0 + px];
    }
    __syncthreads();
    for (int idx = tid; idx < 64 * 24; idx += 256) {
        int px = idx / 24, grp = idx % 24;
        union { unsigned short u[8]; uint4 v; } pk;
#pragma unroll
        for (int j = 0; j < 8; ++j) pk.u[j] = bfbits(xs[grp * 8 + j][px]);
        *reinterpret_cast<uint4*>(
            &outp[(((long long)b * HH + y) * WW + x0 + px) * CDIM + grp * 8]) = pk.v;
    }
}

// ---------------------------------------------------------------------------
// Pack kv_w (OIHW fp32) -> Wpack[oc][tap][ic] bf16 (k-contiguous A operand).
// ---------------------------------------------------------------------------
__global__ __launch_bounds__(256) void pack_w_kernel(
    const float* __restrict__ w, unsigned short* __restrict__ wp)
{
    int idx = blockIdx.x * 256 + threadIdx.x;
    if (idx >= 384 * 9 * 192) return;
    int ic = idx % 192;
    int tap = (idx / 192) % 9;
    int oc = idx / (192 * 9);
    wp[idx] = bfbits(w[((long long)oc * 192 + ic) * 9 + tap]);
}

// ---------------------------------------------------------------------------
// Dense 3x3 conv 192->384 via MFMA implicit GEMM.
// Inputs: Xbf NHWC bf16 [b][y][x][192], Wpack [oc][9][192] bf16.
// Output: bf16 NCHW [b][384][y][x].
// Block 256 thr = 4 waves (2 oc x 2 px); block tile 64 oc x 128 px (one row).
// Wave tile 32 oc x 64 px: per (tap, ic32): 2 A-frags, 4 B-frags, 8 MFMA.
// LDS: xs[3][130][104] bf16 (81 KB), ic-chunked 96 at a time.
// ---------------------------------------------------------------------------
#define ICP 104

__global__ __launch_bounds__(256) void conv3x3_mfma_kernel(
    const unsigned short* __restrict__ Xbf,
    const unsigned short* __restrict__ Wpack,
    const float* __restrict__ bias,
    bf16* __restrict__ out)
{
    __shared__ unsigned short xs[3][130][ICP];
    int tid = threadIdx.x;
    int lane = tid & 63;
    int wave = tid >> 6;
    int w_oc = wave >> 1;        // 0..1
    int w_px = wave & 1;         // 0..1
    int l15 = lane & 15;
    int lk = lane >> 4;          // 0..3

    int y = blockIdx.x;
    int ocb = blockIdx.y * 64;
    int b = blockIdx.z;
    int ocw = ocb + w_oc * 32;

    f32x4 acc[2][4];
#pragma unroll
    for (int mi = 0; mi < 2; ++mi) {
#pragma unroll
        for (int r = 0; r < 4; ++r) {
            float bz = bias[ocw + mi * 16 + lk * 4 + r];
#pragma unroll
            for (int nf = 0; nf < 4; ++nf) acc[mi][nf][r] = bz;
        }
    }

    for (int chunk = 0; chunk < 2; ++chunk) {
        int ic0 = chunk * 96;
        __syncthreads();
        // stage [3 rows][130 cols][96 ic] bf16, 16 B per thread-iter
        for (int idx = tid; idx < 3 * 130 * 12; idx += 256) {
            int grp = idx % 12;
            int col = (idx / 12) % 130;
            int ky = idx / (12 * 130);
            int yy = y + ky - 1;
            int xx = col - 1;
            uint4 val = make_uint4(0u, 0u, 0u, 0u);
            if (yy >= 0 && yy < HH && xx >= 0 && xx < WW)
                val = *reinterpret_cast<const uint4*>(
                    &Xbf[(((long long)b * HH + yy) * WW + xx) * CDIM + ic0 + grp * 8]);
            *reinterpret_cast<uint4*>(&xs[ky][col][grp * 8]) = val;
        }
        __syncthreads();

#pragma unroll
        for (int tap = 0; tap < 9; ++tap) {
            int ky = tap / 3, kx = tap % 3;
#pragma unroll
            for (int icb2 = 0; icb2 < 96; icb2 += 32) {
                bf16x8 a[2];
#pragma unroll
                for (int mi = 0; mi < 2; ++mi) {
                    int oc = ocw + mi * 16 + l15;
                    a[mi] = *reinterpret_cast<const bf16x8*>(
                        &Wpack[(((long long)oc * 9 + tap) * CDIM) + ic0 + icb2 + lk * 8]);
                }
                bf16x8 bv[4];
#pragma unroll
                for (int nf = 0; nf < 4; ++nf) {
                    int col = w_px * 64 + nf * 16 + l15 + kx;
                    bv[nf] = *reinterpret_cast<const bf16x8*>(&xs[ky][col][icb2 + lk * 8]);
                }
#pragma unroll
                for (int mi = 0; mi < 2; ++mi)
#pragma unroll
                    for (int nf = 0; nf < 4; ++nf)
                        acc[mi][nf] = __builtin_amdgcn_mfma_f32_16x16x32_bf16(
                            a[mi], bv[nf], acc[mi][nf], 0, 0, 0);
            }
        }
    }

    // store: C frag mapping col(px)=lane&15, row(oc)=(lane>>4)*4+reg
#pragma unroll
    for (int mi = 0; mi < 2; ++mi) {
#pragma unroll
        for (int nf = 0; nf < 4; ++nf) {
            int x = w_px * 64 + nf * 16 + l15;
#pragma unroll
            for (int r = 0; r < 4; ++r) {
                int oc = ocw + mi * 16 + lk * 4 + r;
                stF(&out[(((long long)b * 384 + oc) << 14) + y * WW + x], acc[mi][nf][r]);
            }
        }
    }
}

// ---------------------------------------------------------------------------
// Reductions: per-channel sumsq q,k,v + 24x24 Gram(q,k). (unchanged)
// ---------------------------------------------------------------------------
__global__ __launch_bounds__(256) void reduce_qkv_kernel(
    const bf16* __restrict__ q, long long bsq,
    const bf16* __restrict__ k, long long bsk,
    const bf16* __restrict__ v, long long bsv,
    float* __restrict__ ssq, float* __restrict__ gram)
{
    __shared__ float qs[24][129], ks[24][129], vs[24][129];
    int bh = blockIdx.x;
    int b = bh >> 3, h = bh & 7;
    int n0 = blockIdx.y * 256;
    int tid = threadIdx.x;

    float ag0 = 0.f, ag1 = 0.f, ag2 = 0.f;
    float accs = 0.f;
    int e0 = tid, e1 = tid + 256, e2 = tid + 512;

    for (int cc = 0; cc < 2; ++cc) {
        int nb = n0 + cc * 128;
        __syncthreads();
        for (int idx = tid; idx < 24 * 128; idx += 256) {
            int c = idx >> 7, i = idx & 127;
            long long off = (long long)(h * CP + c) * NPIX + nb + i;
            qs[c][i] = toF(q[(long long)b * bsq + off]);
            ks[c][i] = toF(k[(long long)b * bsk + off]);
            vs[c][i] = toF(v[(long long)b * bsv + off]);
        }
        __syncthreads();
        {
            int cq = e0 / 24, ck = e0 % 24;
            for (int i = 0; i < 128; ++i) ag0 = fmaf(qs[cq][i], ks[ck][i], ag0);
        }
        {
            int cq = e1 / 24, ck = e1 % 24;
            for (int i = 0; i < 128; ++i) ag1 = fmaf(qs[cq][i], ks[ck][i], ag1);
        }
        if (tid < 64) {
            int cq = e2 / 24, ck = e2 % 24;
            for (int i = 0; i < 128; ++i) ag2 = fmaf(qs[cq][i], ks[ck][i], ag2);
        }
        if (tid < 72) {
            int tensor = tid / 24, c = tid % 24;
            const float (*src)[129] = (tensor == 0) ? qs : (tensor == 1) ? ks : vs;
            for (int i = 0; i < 128; ++i) accs = fmaf(src[c][i], src[c][i], accs);
        }
    }
    float* gb = gram + (long long)bh * 576;
    atomicAdd(&gb[e0], ag0);
    atomicAdd(&gb[e1], ag1);
    if (tid < 64) atomicAdd(&gb[e2], ag2);
    if (tid < 72) {
        int tensor = tid / 24, c = tid % 24;
        atomicAdd(&ssq[tensor * (NB * CDIM) + b * CDIM + h * CP + c], accs);
    }
}

// ---------------------------------------------------------------------------
// Softmax + fold norms + proj into per-batch M (192x192). (unchanged)
// ---------------------------------------------------------------------------
__global__ __launch_bounds__(256) void build_M_kernel(
    const float* __restrict__ ssq, const float* __restrict__ gram,
    const float* __restrict__ temp, const float* __restrict__ proj_w,
    float* __restrict__ M)
{
    __shared__ float A[HEADS][CP][CP];
    __shared__ float nq[CDIM], nk[CDIM], nv[CDIM];
    int b = blockIdx.x;
    int tid = threadIdx.x;
    if (tid < CDIM) {
        nq[tid] = fmaxf(sqrtf(ssq[0 * (NB * CDIM) + b * CDIM + tid]), 1e-12f);
        nk[tid] = fmaxf(sqrtf(ssq[1 * (NB * CDIM) + b * CDIM + tid]), 1e-12f);
        nv[tid] = fmaxf(sqrtf(ssq[2 * (NB * CDIM) + b * CDIM + tid]), 1e-12f);
    }
    __syncthreads();
    if (tid < CDIM) {
        int h = tid / CP, cq = tid % CP;
        float t = temp[h];
        float row[CP];
        float m = -1e30f;
#pragma unroll
        for (int ck = 0; ck < CP; ++ck) {
            float g = gram[(long long)b * (HEADS * 576) + h * 576 + cq * CP + ck];
            g = g / (nq[h * CP + cq] * nk[h * CP + ck]) * t;
            row[ck] = g;
            m = fmaxf(m, g);
        }
        float s = 0.f;
#pragma unroll
        for (int ck = 0; ck < CP; ++ck) { row[ck] = __expf(row[ck] - m); s += row[ck]; }
        float inv = 1.f / s;
#pragma unroll
        for (int ck = 0; ck < CP; ++ck)
            A[h][cq][ck] = row[ck] * inv / nv[h * CP + ck];
    }
    __syncthreads();
    for (int e = tid; e < CDIM * CDIM; e += 256) {
        int oc = e / CDIM, d = e % CDIM;
        int h2 = d / CP, ck = d % CP;
        float acc = 0.f;
#pragma unroll
        for (int cq = 0; cq < CP; ++cq)
            acc = fmaf(proj_w[(long long)oc * CDIM + h2 * CP + cq], A[h2][cq][ck], acc);
        M[(long long)b * (CDIM * CDIM) + e] = acc;
    }
}

__global__ void zero_kernel(float* __restrict__ p, int n)
{
    for (int i = blockIdx.x * 256 + threadIdx.x; i < n; i += gridDim.x * 256) p[i] = 0.f;
}

// ---------------------------------------------------------------------------
// Workspace layout (bytes), identical footprint to round 2 (~202 MB):
//   A:  bf16[37,748,736]  [0          : 75,497,472)
//        - S1 writes qkv1 (full region)
//        - after S2: conv3x3 output occupies [0 : 25.17M elems),
//          Xbf (NHWC x_mask) occupies [25.17M : 37.75M elems)  (exact fit)
//        - then k_new/v_new at [0 : 25.17M elems)
//   B:  bf16[37,748,736]  [75,497,472 : 150,994,944)  qkv (post grouped conv)
//   C:  bf16[25,165,824]  [150,994,944: 201,326,592)  Wpack (transient) -> kv2
//   stats: float          [201,326,592: 201,999,360)  ssq | gram | M
// ---------------------------------------------------------------------------
extern "C" void kernel_launch(void* const* d_in, const int* in_sizes, int n_in,
                              void* d_out, int out_size, void* d_ws, size_t ws_size,
                              hipStream_t stream)
{
    const float* x      = (const float*)d_in[0];
    const float* x_mask = (const float*)d_in[1];
    const float* temp   = (const float*)d_in[2];
    const float* q_w    = (const float*)d_in[3];
    const float* q_b    = (const float*)d_in[4];
    const float* qdw_w  = (const float*)d_in[5];
    const float* qdw_b  = (const float*)d_in[6];
    const float* kv_w   = (const float*)d_in[7];
    const float* kv_b   = (const float*)d_in[8];
    const float* kvdw_w = (const float*)d_in[9];
    const float* kvdw_b = (const float*)d_in[10];
    const float* newk_w = (const float*)d_in[11];
    const float* newk_b = (const float*)d_in[12];
    const float* newv_w = (const float*)d_in[13];
    const float* newv_b = (const float*)d_in[14];
    const float* proj_w = (const float*)d_in[15];
    const float* proj_b = (const float*)d_in[16];

    char* wsb = (char*)d_ws;
    bf16* A  = (bf16*)wsb;                             // 37,748,736 elems
    bf16* Bq = (bf16*)(wsb + 75497472);                // 37,748,736 elems
    bf16* C  = (bf16*)(wsb + 150994944);               // 25,165,824 elems
    unsigned short* Xbf   = (unsigned short*)A + 25165824;  // 12,582,912 elems (A tail)
    unsigned short* Wpack = (unsigned short*)C;              // 663,552 elems (transient)
    float* stats = (float*)(wsb + 201326592);
    float* ssq  = stats;                               // 2304
    float* gram = ssq + 2304;                          // 18432
    float* Mbuf = gram + 18432;                        // 147456

    const long long N = NPIX;
    float* out = (float*)d_out;

    // zero the atomic-accumulated stats
    zero_kernel<<<16, 256, 0, stream>>>(ssq, 2304 + 18432);

    // S1: qkv1 = conv1x1(x, q_w) : 192 -> 576  (fp32 in, bf16 out) -> A
    gemm1x1_kernel<float, bf16><<<dim3(256, 18, 4), 256, 0, stream>>>(
        x, 192 * N, (const float*)nullptr, 0, 192, 192, q_w, 0, q_b, A, 576 * N);

    // S2: qkv = grouped 3x3 (groups=192, 3in/3out) -> B
    dwconv3x3_kernel<3, 3><<<dim3(32, 192, 4), 128, 0, stream>>>(
        A, qdw_w, qdw_b, Bq, 192);

    // S3-prep: pack weights -> Wpack (C region), convert x_mask -> Xbf (A tail)
    pack_w_kernel<<<(384 * 9 * 192 + 255) / 256, 256, 0, stream>>>(kv_w, Wpack);
    nchw2nhwc_kernel<<<dim3(256, 1, 4), 256, 0, stream>>>(x_mask, Xbf);

    // S3: kv1 = dense conv3x3(x_mask) 192->384 via MFMA -> A[0:25.17M)
    conv3x3_mfma_kernel<<<dim3(128, 6, 4), 256, 0, stream>>>(Xbf, Wpack, kv_b, A);

    // S4: kv2 = depthwise 3x3 (384 groups) -> C (overwrites Wpack, done with it)
    dwconv3x3_kernel<1, 1><<<dim3(32, 384, 4), 128, 0, stream>>>(
        A, kvdw_w, kvdw_b, C, 384);

    // S5: k_new = conv1x1([k ; k_mask], newk_w); v_new likewise -> A (reuse)
    bf16* k_new = A;
    bf16* v_new = A + 12582912;
    gemm1x1_kernel<bf16, bf16><<<dim3(256, 6, 4), 256, 0, stream>>>(
        Bq + 192 * N, 576 * N, C, 384 * N, 192, 384, newk_w, 0, newk_b,
        k_new, 192 * N);
    gemm1x1_kernel<bf16, bf16><<<dim3(256, 6, 4), 256, 0, stream>>>(
        Bq + 384 * N, 576 * N, C + 192 * N, 384 * N, 192, 384, newv_w, 0, newv_b,
        v_new, 192 * N);

    // S6: sumsq(q,k,v) + Gram(q,k)
    reduce_qkv_kernel<<<dim3(32, 64), 256, 0, stream>>>(
        Bq, 576 * N, k_new, 192 * N, v_new, 192 * N, ssq, gram);

    // S7: softmax + fold v-norm + proj -> per-batch M (192x192)
    build_M_kernel<<<4, 256, 0, stream>>>(ssq, gram, temp, proj_w, Mbuf);

    // S8: out = M_b @ v_new + proj_b  (bf16 in, fp32 out)
    gemm1x1_kernel<bf16, float><<<dim3(256, 6, 4), 256, 0, stream>>>(
        v_new, 192 * N, (const bf16*)nullptr, 0, 192, 192, Mbuf,
        (long long)CDIM * CDIM, proj_b, out, 192 * N);
}

// Round 4
// 803.613 us; speedup vs baseline: 11.1723x; 3.4725x over previous
//
#include <hip/hip_runtime.h>
#include <hip/hip_bf16.h>

// Problem constants
#define NB 4
#define CDIM 192
#define HEADS 8
#define CP 24
#define HH 128
#define WW 128
#define NPIX 16384  // 128*128

typedef __hip_bfloat16 bf16;
typedef __bf16 bf16x8 __attribute__((ext_vector_type(8)));
typedef float f32x4 __attribute__((ext_vector_type(4)));

__device__ __forceinline__ float toF(float v) { return v; }
__device__ __forceinline__ float toF(bf16 v) { return __bfloat162float(v); }
__device__ __forceinline__ void stF(float* p, float v) { *p = v; }
__device__ __forceinline__ void stF(bf16* p, float v) { *p = __float2bfloat16(v); }
__device__ __forceinline__ unsigned short bfbits(float v) {
    bf16 h = __float2bfloat16(v);
    return *reinterpret_cast<unsigned short*>(&h);
}

// ---------------------------------------------------------------------------
// 1x1-conv / per-pixel GEMM via bf16 MFMA.
// out[b,oc,n] = bias[oc] + sum_ic W[oc,ic] * in(ch)[b,n]; ch<ic_split -> in0,
// else in1. Planar NCHW operands; LDS transpose-staging [128px][64ic] bf16
// (pad 72, XOR swizzle (ic^((px>>2)&7)*8) for bank spread).
// Block 256 thr = 4 waves (2 oc x 2 px); tile 64 oc x 128 px.
// Weights: packed bf16 [oc][IC], k-contiguous (one 16B load per A-frag).
// ---------------------------------------------------------------------------
template <typename TI, typename TO>
__global__ __launch_bounds__(256) void gemm1x1_mfma_kernel(
    const TI* __restrict__ in0, long long bs0,
    const TI* __restrict__ in1, long long bs1, int ic_split,
    int IC, const unsigned short* __restrict__ Wbf, long long w_bs,
    const float* __restrict__ bias,
    TO* __restrict__ out, long long bs_out)
{
    __shared__ unsigned short xs[128][72];
    int tid = threadIdx.x;
    int lane = tid & 63;
    int wave = tid >> 6;
    int w_oc = wave >> 1;
    int w_px = wave & 1;
    int l15 = lane & 15;
    int lk  = lane >> 4;

    int nb  = blockIdx.x * 128;
    int b   = blockIdx.z;
    int ocw = blockIdx.y * 64 + w_oc * 32;
    const unsigned short* Wb = Wbf + (long long)b * w_bs;

    f32x4 acc[2][4];
#pragma unroll
    for (int mi = 0; mi < 2; ++mi)
#pragma unroll
        for (int r = 0; r < 4; ++r) {
            float bz = bias[ocw + mi * 16 + lk * 4 + r];
#pragma unroll
            for (int nf = 0; nf < 4; ++nf) acc[mi][nf][r] = bz;
        }

    for (int icb = 0; icb < IC; icb += 64) {
        __syncthreads();
        // stage 64 ic x 128 px: each thread 2 micro-tiles of 4ic x 4px
#pragma unroll
        for (int it = 0; it < 2; ++it) {
            int u = tid + it * 256;
            int px = (u & 31) * 4;
            int ic = (u >> 5) * 4;
            unsigned short rb[4][4];
#pragma unroll
            for (int j = 0; j < 4; ++j) {
                int ch = icb + ic + j;
                const TI* p;
                if (ch < ic_split)
                    p = in0 + (long long)b * bs0 + (long long)ch * NPIX + nb + px;
                else
                    p = in1 + (long long)b * bs1 + (long long)(ch - ic_split) * NPIX + nb + px;
                if constexpr (sizeof(TI) == 4) {
                    float4 v = *reinterpret_cast<const float4*>(p);
                    rb[j][0] = bfbits(v.x); rb[j][1] = bfbits(v.y);
                    rb[j][2] = bfbits(v.z); rb[j][3] = bfbits(v.w);
                } else {
                    ushort4 v = *reinterpret_cast<const ushort4*>(p);
                    rb[j][0] = v.x; rb[j][1] = v.y; rb[j][2] = v.z; rb[j][3] = v.w;
                }
            }
            int swz = ((px >> 2) & 7) * 8;
#pragma unroll
            for (int i = 0; i < 4; ++i) {
                union { unsigned short s[4]; uint2 v; } pk;
                pk.s[0] = rb[0][i]; pk.s[1] = rb[1][i];
                pk.s[2] = rb[2][i]; pk.s[3] = rb[3][i];
                *reinterpret_cast<uint2*>(&xs[px + i][ic ^ swz]) = pk.v;
            }
        }
        __syncthreads();

#pragma unroll
        for (int ks = 0; ks < 2; ++ks) {
            int koff = ks * 32 + lk * 8;
            bf16x8 a[2], bv[4];
#pragma unroll
            for (int mi = 0; mi < 2; ++mi)
                a[mi] = *reinterpret_cast<const bf16x8*>(
                    &Wb[(long long)(ocw + mi * 16 + l15) * IC + icb + koff]);
#pragma unroll
            for (int nf = 0; nf < 4; ++nf) {
                int px = w_px * 64 + nf * 16 + l15;
                int swzr = ((px >> 2) & 7) * 8;
                bv[nf] = *reinterpret_cast<const bf16x8*>(&xs[px][koff ^ swzr]);
            }
#pragma unroll
            for (int mi = 0; mi < 2; ++mi)
#pragma unroll
                for (int nf = 0; nf < 4; ++nf)
                    acc[mi][nf] = __builtin_amdgcn_mfma_f32_16x16x32_bf16(
                        a[mi], bv[nf], acc[mi][nf], 0, 0, 0);
        }
    }

    // C frag: col(px)=lane&15, row(oc)=(lane>>4)*4+reg
#pragma unroll
    for (int mi = 0; mi < 2; ++mi)
#pragma unroll
        for (int nf = 0; nf < 4; ++nf) {
            int x = w_px * 64 + nf * 16 + l15;
#pragma unroll
            for (int r = 0; r < 4; ++r) {
                int oc = ocw + mi * 16 + lk * 4 + r;
                stF(&out[(long long)b * bs_out + (long long)oc * NPIX + nb + x],
                    acc[mi][nf][r]);
            }
        }
}

// ---------------------------------------------------------------------------
// Grouped / depthwise 3x3 conv, pad 1 (unchanged).
// ---------------------------------------------------------------------------
template <int GIN, int GOUT>
__global__ __launch_bounds__(128) void dwconv3x3_kernel(
    const bf16* __restrict__ in, const float* __restrict__ Wm,
    const float* __restrict__ bias, bf16* __restrict__ out, int groups)
{
    __shared__ float xs[GIN][6][130];
    int x = threadIdx.x;
    int g = blockIdx.y;
    int b = blockIdx.z;
    int y0 = blockIdx.x * 4;
    long long bsin = (long long)groups * GIN * NPIX;
    long long bsout = (long long)groups * GOUT * NPIX;

#pragma unroll
    for (int ic = 0; ic < GIN; ++ic) {
        for (int r = 0; r < 6; ++r) {
            int yy = y0 + r - 1;
            float v = 0.f;
            if (yy >= 0 && yy < HH)
                v = toF(in[(long long)b * bsin + (long long)(g * GIN + ic) * NPIX + yy * WW + x]);
            xs[ic][r][x + 1] = v;
            if (x == 0) { xs[ic][r][0] = 0.f; xs[ic][r][129] = 0.f; }
        }
    }
    __syncthreads();

    for (int j = 0; j < GOUT; ++j) {
        int oc = g * GOUT + j;
        const float* wp = Wm + (long long)oc * GIN * 9;
        float bj = bias[oc];
        for (int ry = 0; ry < 4; ++ry) {
            float acc = bj;
#pragma unroll
            for (int ic = 0; ic < GIN; ++ic)
#pragma unroll
                for (int ky = 0; ky < 3; ++ky)
#pragma unroll
                    for (int kx = 0; kx < 3; ++kx)
                        acc = fmaf(wp[ic * 9 + ky * 3 + kx], xs[ic][ry + ky][x + kx], acc);
            stF(&out[(long long)b * bsout + (long long)oc * NPIX + (y0 + ry) * WW + x], acc);
        }
    }
}

// ---------------------------------------------------------------------------
// NCHW fp32 -> NHWC bf16 transpose-convert (B operand of the MFMA conv).
// ---------------------------------------------------------------------------
__global__ __launch_bounds__(256) void nchw2nhwc_kernel(
    const float* __restrict__ in, unsigned short* __restrict__ outp)
{
    __shared__ float xs[192][65];
    int tid = threadIdx.x;
    int y = blockIdx.x >> 1;
    int x0 = (blockIdx.x & 1) * 64;
    int b = blockIdx.z;

    for (int idx = tid; idx < 192 * 64; idx += 256) {
        int ic = idx >> 6, px = idx & 63;
        xs[ic][px] = in[(((long long)b * CDIM + ic) << 14) + y * WW + x0 + px];
    }
    __syncthreads();
    for (int idx = tid; idx < 64 * 24; idx += 256) {
        int px = idx / 24, grp = idx % 24;
        union { unsigned short u[8]; uint4 v; } pk;
#pragma unroll
        for (int j = 0; j < 8; ++j) pk.u[j] = bfbits(xs[grp * 8 + j][px]);
        *reinterpret_cast<uint4*>(
            &outp[(((long long)b * HH + y) * WW + x0 + px) * CDIM + grp * 8]) = pk.v;
    }
}

// ---------------------------------------------------------------------------
// Pack kv_w (OIHW fp32) -> Wpack[oc][tap][ic] bf16.
// ---------------------------------------------------------------------------
__global__ __launch_bounds__(256) void pack_w_kernel(
    const float* __restrict__ w, unsigned short* __restrict__ wp)
{
    int idx = blockIdx.x * 256 + threadIdx.x;
    if (idx >= 384 * 9 * 192) return;
    int ic = idx % 192;
    int tap = (idx / 192) % 9;
    int oc = idx / (192 * 9);
    wp[idx] = bfbits(w[((long long)oc * 192 + ic) * 9 + tap]);
}

// ---------------------------------------------------------------------------
// Generic fp32 -> bf16 bit convert (for [oc][ic]-contiguous weight matrices).
// ---------------------------------------------------------------------------
__global__ __launch_bounds__(256) void cvt_bf16_kernel(
    const float* __restrict__ src, unsigned short* __restrict__ dst, int n)
{
    int i = blockIdx.x * 256 + threadIdx.x;
    if (i < n) dst[i] = bfbits(src[i]);
}

// ---------------------------------------------------------------------------
// Dense 3x3 conv 192->384 via MFMA implicit GEMM (unchanged).
// ---------------------------------------------------------------------------
#define ICP 104

__global__ __launch_bounds__(256) void conv3x3_mfma_kernel(
    const unsigned short* __restrict__ Xbf,
    const unsigned short* __restrict__ Wpack,
    const float* __restrict__ bias,
    bf16* __restrict__ out)
{
    __shared__ unsigned short xs[3][130][ICP];
    int tid = threadIdx.x;
    int lane = tid & 63;
    int wave = tid >> 6;
    int w_oc = wave >> 1;
    int w_px = wave & 1;
    int l15 = lane & 15;
    int lk = lane >> 4;

    int y = blockIdx.x;
    int ocb = blockIdx.y * 64;
    int b = blockIdx.z;
    int ocw = ocb + w_oc * 32;

    f32x4 acc[2][4];
#pragma unroll
    for (int mi = 0; mi < 2; ++mi) {
#pragma unroll
        for (int r = 0; r < 4; ++r) {
            float bz = bias[ocw + mi * 16 + lk * 4 + r];
#pragma unroll
            for (int nf = 0; nf < 4; ++nf) acc[mi][nf][r] = bz;
        }
    }

    for (int chunk = 0; chunk < 2; ++chunk) {
        int ic0 = chunk * 96;
        __syncthreads();
        for (int idx = tid; idx < 3 * 130 * 12; idx += 256) {
            int grp = idx % 12;
            int col = (idx / 12) % 130;
            int ky = idx / (12 * 130);
            int yy = y + ky - 1;
            int xx = col - 1;
            uint4 val = make_uint4(0u, 0u, 0u, 0u);
            if (yy >= 0 && yy < HH && xx >= 0 && xx < WW)
                val = *reinterpret_cast<const uint4*>(
                    &Xbf[(((long long)b * HH + yy) * WW + xx) * CDIM + ic0 + grp * 8]);
            *reinterpret_cast<uint4*>(&xs[ky][col][grp * 8]) = val;
        }
        __syncthreads();

#pragma unroll
        for (int tap = 0; tap < 9; ++tap) {
            int ky = tap / 3, kx = tap % 3;
#pragma unroll
            for (int icb2 = 0; icb2 < 96; icb2 += 32) {
                bf16x8 a[2];
#pragma unroll
                for (int mi = 0; mi < 2; ++mi) {
                    int oc = ocw + mi * 16 + l15;
                    a[mi] = *reinterpret_cast<const bf16x8*>(
                        &Wpack[(((long long)oc * 9 + tap) * CDIM) + ic0 + icb2 + lk * 8]);
                }
                bf16x8 bv[4];
#pragma unroll
                for (int nf = 0; nf < 4; ++nf) {
                    int col = w_px * 64 + nf * 16 + l15 + kx;
                    bv[nf] = *reinterpret_cast<const bf16x8*>(&xs[ky][col][icb2 + lk * 8]);
                }
#pragma unroll
                for (int mi = 0; mi < 2; ++mi)
#pragma unroll
                    for (int nf = 0; nf < 4; ++nf)
                        acc[mi][nf] = __builtin_amdgcn_mfma_f32_16x16x32_bf16(
                            a[mi], bv[nf], acc[mi][nf], 0, 0, 0);
            }
        }
    }

#pragma unroll
    for (int mi = 0; mi < 2; ++mi) {
#pragma unroll
        for (int nf = 0; nf < 4; ++nf) {
            int x = w_px * 64 + nf * 16 + l15;
#pragma unroll
            for (int r = 0; r < 4; ++r) {
                int oc = ocw + mi * 16 + lk * 4 + r;
                stF(&out[(((long long)b * 384 + oc) << 14) + y * WW + x], acc[mi][nf][r]);
            }
        }
    }
}

// ---------------------------------------------------------------------------
// Reductions: per-channel sumsq q,k,v + 24x24 Gram(q,k). (unchanged)
// ---------------------------------------------------------------------------
__global__ __launch_bounds__(256) void reduce_qkv_kernel(
    const bf16* __restrict__ q, long long bsq,
    const bf16* __restrict__ k, long long bsk,
    const bf16* __restrict__ v, long long bsv,
    float* __restrict__ ssq, float* __restrict__ gram)
{
    __shared__ float qs[24][129], ks[24][129], vs[24][129];
    int bh = blockIdx.x;
    int b = bh >> 3, h = bh & 7;
    int n0 = blockIdx.y * 256;
    int tid = threadIdx.x;

    float ag0 = 0.f, ag1 = 0.f, ag2 = 0.f;
    float accs = 0.f;
    int e0 = tid, e1 = tid + 256, e2 = tid + 512;

    for (int cc = 0; cc < 2; ++cc) {
        int nb = n0 + cc * 128;
        __syncthreads();
        for (int idx = tid; idx < 24 * 128; idx += 256) {
            int c = idx >> 7, i = idx & 127;
            long long off = (long long)(h * CP + c) * NPIX + nb + i;
            qs[c][i] = toF(q[(long long)b * bsq + off]);
            ks[c][i] = toF(k[(long long)b * bsk + off]);
            vs[c][i] = toF(v[(long long)b * bsv + off]);
        }
        __syncthreads();
        {
            int cq = e0 / 24, ck = e0 % 24;
            for (int i = 0; i < 128; ++i) ag0 = fmaf(qs[cq][i], ks[ck][i], ag0);
        }
        {
            int cq = e1 / 24, ck = e1 % 24;
            for (int i = 0; i < 128; ++i) ag1 = fmaf(qs[cq][i], ks[ck][i], ag1);
        }
        if (tid < 64) {
            int cq = e2 / 24, ck = e2 % 24;
            for (int i = 0; i < 128; ++i) ag2 = fmaf(qs[cq][i], ks[ck][i], ag2);
        }
        if (tid < 72) {
            int tensor = tid / 24, c = tid % 24;
            const float (*src)[129] = (tensor == 0) ? qs : (tensor == 1) ? ks : vs;
            for (int i = 0; i < 128; ++i) accs = fmaf(src[c][i], src[c][i], accs);
        }
    }
    float* gb = gram + (long long)bh * 576;
    atomicAdd(&gb[e0], ag0);
    atomicAdd(&gb[e1], ag1);
    if (tid < 64) atomicAdd(&gb[e2], ag2);
    if (tid < 72) {
        int tensor = tid / 24, c = tid % 24;
        atomicAdd(&ssq[tensor * (NB * CDIM) + b * CDIM + h * CP + c], accs);
    }
}

// ---------------------------------------------------------------------------
// Softmax + fold norms + proj into per-batch M (192x192), output bf16.
// ---------------------------------------------------------------------------
__global__ __launch_bounds__(256) void build_M_kernel(
    const float* __restrict__ ssq, const float* __restrict__ gram,
    const float* __restrict__ temp, const float* __restrict__ proj_w,
    unsigned short* __restrict__ Mout)
{
    __shared__ float A[HEADS][CP][CP];
    __shared__ float nq[CDIM], nk[CDIM], nv[CDIM];
    int b = blockIdx.x;
    int tid = threadIdx.x;
    if (tid < CDIM) {
        nq[tid] = fmaxf(sqrtf(ssq[0 * (NB * CDIM) + b * CDIM + tid]), 1e-12f);
        nk[tid] = fmaxf(sqrtf(ssq[1 * (NB * CDIM) + b * CDIM + tid]), 1e-12f);
        nv[tid] = fmaxf(sqrtf(ssq[2 * (NB * CDIM) + b * CDIM + tid]), 1e-12f);
    }
    __syncthreads();
    if (tid < CDIM) {
        int h = tid / CP, cq = tid % CP;
        float t = temp[h];
        float row[CP];
        float m = -1e30f;
#pragma unroll
        for (int ck = 0; ck < CP; ++ck) {
            float g = gram[(long long)b * (HEADS * 576) + h * 576 + cq * CP + ck];
            g = g / (nq[h * CP + cq] * nk[h * CP + ck]) * t;
            row[ck] = g;
            m = fmaxf(m, g);
        }
        float s = 0.f;
#pragma unroll
        for (int ck = 0; ck < CP; ++ck) { row[ck] = __expf(row[ck] - m); s += row[ck]; }
        float inv = 1.f / s;
#pragma unroll
        for (int ck = 0; ck < CP; ++ck)
            A[h][cq][ck] = row[ck] * inv / nv[h * CP + ck];
    }
    __syncthreads();
    for (int e = tid; e < CDIM * CDIM; e += 256) {
        int oc = e / CDIM, d = e % CDIM;
        int h2 = d / CP, ck = d % CP;
        float acc = 0.f;
#pragma unroll
        for (int cq = 0; cq < CP; ++cq)
            acc = fmaf(proj_w[(long long)oc * CDIM + h2 * CP + cq], A[h2][cq][ck], acc);
        Mout[(long long)b * (CDIM * CDIM) + e] = bfbits(acc);
    }
}

__global__ void zero_kernel(float* __restrict__ p, int n)
{
    for (int i = blockIdx.x * 256 + threadIdx.x; i < n; i += gridDim.x * 256) p[i] = 0.f;
}

// ---------------------------------------------------------------------------
// Workspace layout (u16 element offsets unless noted), total < 202 MB:
//   A u16[37,748,736] @ 0 B:
//     S1 qkv1 (full) -> S3 kv1 [0:25,165,824) -> k_new [0:12,582,912),
//     v_new [12,582,912:25,165,824)
//     tail (free after S2): nkb @25,165,824 (73,728), nvb @25,239,552 (73,728),
//     Mbf @25,313,280 (147,456)
//   B u16[37,748,736] @ 75,497,472 B:
//     qwb [0:110,592) (pre-S1) -> S2 qkv (full)
//   C u16[25,165,824] @ 150,994,944 B:
//     Wpack [0:663,552), Xbf [663,552:13,246,464) -> S4 kv2 (full)
//   stats f32 @ 201,326,592 B: ssq 2304 | gram 18432  (ends 201,409,536 B)
// ---------------------------------------------------------------------------
extern "C" void kernel_launch(void* const* d_in, const int* in_sizes, int n_in,
                              void* d_out, int out_size, void* d_ws, size_t ws_size,
                              hipStream_t stream)
{
    const float* x      = (const float*)d_in[0];
    const float* x_mask = (const float*)d_in[1];
    const float* temp   = (const float*)d_in[2];
    const float* q_w    = (const float*)d_in[3];
    const float* q_b    = (const float*)d_in[4];
    const float* qdw_w  = (const float*)d_in[5];
    const float* qdw_b  = (const float*)d_in[6];
    const float* kv_w   = (const float*)d_in[7];
    const float* kv_b   = (const float*)d_in[8];
    const float* kvdw_w = (const float*)d_in[9];
    const float* kvdw_b = (const float*)d_in[10];
    const float* newk_w = (const float*)d_in[11];
    const float* newk_b = (const float*)d_in[12];
    const float* newv_w = (const float*)d_in[13];
    const float* newv_b = (const float*)d_in[14];
    const float* proj_w = (const float*)d_in[15];
    const float* proj_b = (const float*)d_in[16];

    char* wsb = (char*)d_ws;
    bf16* A  = (bf16*)wsb;
    bf16* Bq = (bf16*)(wsb + 75497472);
    bf16* C  = (bf16*)(wsb + 150994944);
    unsigned short* qwb   = (unsigned short*)Bq;                    // 110,592
    unsigned short* nkb   = (unsigned short*)A + 25165824;          // 73,728
    unsigned short* nvb   = (unsigned short*)A + 25239552;          // 73,728
    unsigned short* Mbf   = (unsigned short*)A + 25313280;          // 147,456
    unsigned short* Wpack = (unsigned short*)C;                     // 663,552
    unsigned short* Xbf   = (unsigned short*)C + 663552;            // 12,582,912
    float* stats = (float*)(wsb + 201326592);
    float* ssq  = stats;                                            // 2304
    float* gram = ssq + 2304;                                       // 18432

    const long long N = NPIX;
    float* out = (float*)d_out;

    // stats zero + weight packs needed before S1
    zero_kernel<<<16, 256, 0, stream>>>(ssq, 2304 + 18432);
    cvt_bf16_kernel<<<432, 256, 0, stream>>>(q_w, qwb, 576 * 192);
    pack_w_kernel<<<(384 * 9 * 192 + 255) / 256, 256, 0, stream>>>(kv_w, Wpack);

    // S1: qkv1 = conv1x1(x, q_w) : 192 -> 576 (fp32 in, bf16 out) -> A
    gemm1x1_mfma_kernel<float, bf16><<<dim3(128, 9, 4), 256, 0, stream>>>(
        x, 192 * N, x, 0, 192, 192, qwb, 0, q_b, A, 576 * N);

    // S2: qkv = grouped 3x3 (groups=192, 3in/3out) -> B (consumes A + qwb slot)
    dwconv3x3_kernel<3, 3><<<dim3(32, 192, 4), 128, 0, stream>>>(
        A, qdw_w, qdw_b, Bq, 192);

    // packs into A-tail (A dead after S2) + NHWC convert into C
    cvt_bf16_kernel<<<288, 256, 0, stream>>>(newk_w, nkb, 192 * 384);
    cvt_bf16_kernel<<<288, 256, 0, stream>>>(newv_w, nvb, 192 * 384);
    nchw2nhwc_kernel<<<dim3(256, 1, 4), 256, 0, stream>>>(x_mask, Xbf);

    // S3: kv1 = dense conv3x3(x_mask) 192->384 via MFMA -> A[0:25.17M)
    conv3x3_mfma_kernel<<<dim3(128, 6, 4), 256, 0, stream>>>(Xbf, Wpack, kv_b, A);

    // S4: kv2 = depthwise 3x3 (384 groups) -> C (overwrites Wpack/Xbf, done)
    dwconv3x3_kernel<1, 1><<<dim3(32, 384, 4), 128, 0, stream>>>(
        A, kvdw_w, kvdw_b, C, 384);

    // S5: k_new / v_new = conv1x1 of concat, MFMA -> A[0:25.17M)
    bf16* k_new = A;
    bf16* v_new = A + 12582912;
    gemm1x1_mfma_kernel<bf16, bf16><<<dim3(128, 3, 4), 256, 0, stream>>>(
        Bq + 192 * N, 576 * N, C, 384 * N, 192, 384, nkb, 0, newk_b,
        k_new, 192 * N);
    gemm1x1_mfma_kernel<bf16, bf16><<<dim3(128, 3, 4), 256, 0, stream>>>(
        Bq + 384 * N, 576 * N, C + 192 * N, 384 * N, 192, 384, nvb, 0, newv_b,
        v_new, 192 * N);

    // S6: sumsq(q,k,v) + Gram(q,k)
    reduce_qkv_kernel<<<dim3(32, 64), 256, 0, stream>>>(
        Bq, 576 * N, k_new, 192 * N, v_new, 192 * N, ssq, gram);

    // S7: softmax + fold v-norm + proj -> per-batch M (bf16)
    build_M_kernel<<<4, 256, 0, stream>>>(ssq, gram, temp, proj_w, Mbf);

    // S8: out = M_b @ v_new + proj_b (bf16 in, fp32 out)
    gemm1x1_mfma_kernel<bf16, float><<<dim3(128, 3, 4), 256, 0, stream>>>(
        v_new, 192 * N, v_new, 0, 192, 192, Mbf, (long long)CDIM * CDIM,
        proj_b, out, 192 * N);
}

// Round 5
// 768.320 us; speedup vs baseline: 11.6855x; 1.0459x over previous
//
#include <hip/hip_runtime.h>
#include <hip/hip_bf16.h>

// Problem constants
#define NB 4
#define CDIM 192
#define HEADS 8
#define CP 24
#define HH 128
#define WW 128
#define NPIX 16384  // 128*128

typedef __hip_bfloat16 bf16;
typedef __bf16 bf16x8 __attribute__((ext_vector_type(8)));
typedef float f32x4 __attribute__((ext_vector_type(4)));

__device__ __forceinline__ float toF(float v) { return v; }
__device__ __forceinline__ float toF(bf16 v) { return __bfloat162float(v); }
__device__ __forceinline__ void stF(float* p, float v) { *p = v; }
__device__ __forceinline__ void stF(bf16* p, float v) { *p = __float2bfloat16(v); }
__device__ __forceinline__ unsigned short bfbits(float v) {
    bf16 h = __float2bfloat16(v);
    return *reinterpret_cast<unsigned short*>(&h);
}
__device__ __forceinline__ float b2f(unsigned short u) {
    union { unsigned int i; float f; } c;
    c.i = ((unsigned int)u) << 16;
    return c.f;
}

// ---------------------------------------------------------------------------
// 1x1-conv / per-pixel GEMM via bf16 MFMA (unchanged this round).
// ---------------------------------------------------------------------------
template <typename TI, typename TO>
__global__ __launch_bounds__(256) void gemm1x1_mfma_kernel(
    const TI* __restrict__ in0, long long bs0,
    const TI* __restrict__ in1, long long bs1, int ic_split,
    int IC, const unsigned short* __restrict__ Wbf, long long w_bs,
    const float* __restrict__ bias,
    TO* __restrict__ out, long long bs_out)
{
    __shared__ unsigned short xs[128][72];
    int tid = threadIdx.x;
    int lane = tid & 63;
    int wave = tid >> 6;
    int w_oc = wave >> 1;
    int w_px = wave & 1;
    int l15 = lane & 15;
    int lk  = lane >> 4;

    int nb  = blockIdx.x * 128;
    int b   = blockIdx.z;
    int ocw = blockIdx.y * 64 + w_oc * 32;
    const unsigned short* Wb = Wbf + (long long)b * w_bs;

    f32x4 acc[2][4];
#pragma unroll
    for (int mi = 0; mi < 2; ++mi)
#pragma unroll
        for (int r = 0; r < 4; ++r) {
            float bz = bias[ocw + mi * 16 + lk * 4 + r];
#pragma unroll
            for (int nf = 0; nf < 4; ++nf) acc[mi][nf][r] = bz;
        }

    for (int icb = 0; icb < IC; icb += 64) {
        __syncthreads();
#pragma unroll
        for (int it = 0; it < 2; ++it) {
            int u = tid + it * 256;
            int px = (u & 31) * 4;
            int ic = (u >> 5) * 4;
            unsigned short rb[4][4];
#pragma unroll
            for (int j = 0; j < 4; ++j) {
                int ch = icb + ic + j;
                const TI* p;
                if (ch < ic_split)
                    p = in0 + (long long)b * bs0 + (long long)ch * NPIX + nb + px;
                else
                    p = in1 + (long long)b * bs1 + (long long)(ch - ic_split) * NPIX + nb + px;
                if constexpr (sizeof(TI) == 4) {
                    float4 v = *reinterpret_cast<const float4*>(p);
                    rb[j][0] = bfbits(v.x); rb[j][1] = bfbits(v.y);
                    rb[j][2] = bfbits(v.z); rb[j][3] = bfbits(v.w);
                } else {
                    ushort4 v = *reinterpret_cast<const ushort4*>(p);
                    rb[j][0] = v.x; rb[j][1] = v.y; rb[j][2] = v.z; rb[j][3] = v.w;
                }
            }
            int swz = ((px >> 2) & 7) * 8;
#pragma unroll
            for (int i = 0; i < 4; ++i) {
                union { unsigned short s[4]; uint2 v; } pk;
                pk.s[0] = rb[0][i]; pk.s[1] = rb[1][i];
                pk.s[2] = rb[2][i]; pk.s[3] = rb[3][i];
                *reinterpret_cast<uint2*>(&xs[px + i][ic ^ swz]) = pk.v;
            }
        }
        __syncthreads();

#pragma unroll
        for (int ks = 0; ks < 2; ++ks) {
            int koff = ks * 32 + lk * 8;
            bf16x8 a[2], bv[4];
#pragma unroll
            for (int mi = 0; mi < 2; ++mi)
                a[mi] = *reinterpret_cast<const bf16x8*>(
                    &Wb[(long long)(ocw + mi * 16 + l15) * IC + icb + koff]);
#pragma unroll
            for (int nf = 0; nf < 4; ++nf) {
                int px = w_px * 64 + nf * 16 + l15;
                int swzr = ((px >> 2) & 7) * 8;
                bv[nf] = *reinterpret_cast<const bf16x8*>(&xs[px][koff ^ swzr]);
            }
#pragma unroll
            for (int mi = 0; mi < 2; ++mi)
#pragma unroll
                for (int nf = 0; nf < 4; ++nf)
                    acc[mi][nf] = __builtin_amdgcn_mfma_f32_16x16x32_bf16(
                        a[mi], bv[nf], acc[mi][nf], 0, 0, 0);
        }
    }

#pragma unroll
    for (int mi = 0; mi < 2; ++mi)
#pragma unroll
        for (int nf = 0; nf < 4; ++nf) {
            int x = w_px * 64 + nf * 16 + l15;
#pragma unroll
            for (int r = 0; r < 4; ++r) {
                int oc = ocw + mi * 16 + lk * 4 + r;
                stF(&out[(long long)b * bs_out + (long long)oc * NPIX + nb + x],
                    acc[mi][nf][r]);
            }
        }
}

// ---------------------------------------------------------------------------
// Grouped / depthwise 3x3 conv, pad 1. 256 threads, ROWS output rows/block,
// ushort4 vectorized staging, ushort2 stores, fp32 compute in LDS.
// ---------------------------------------------------------------------------
template <int GIN, int GOUT, int ROWS>
__global__ __launch_bounds__(256) void dwconv3x3_kernel(
    const bf16* __restrict__ in, const float* __restrict__ Wm,
    const float* __restrict__ bias, bf16* __restrict__ out, int groups)
{
    __shared__ float xs[GIN][ROWS + 2][132];
    int tid = threadIdx.x;
    int g = blockIdx.y;
    int b = blockIdx.z;
    int y0 = blockIdx.x * ROWS;
    long long bsin = (long long)groups * GIN * NPIX;
    long long bsout = (long long)groups * GOUT * NPIX;
    const bf16* inb = in + (long long)b * bsin;

    constexpr int NLOAD = GIN * (ROWS + 2) * 32;  // ushort4 loads
    for (int idx = tid; idx < NLOAD; idx += 256) {
        int seg = idx & 31;
        int r = (idx >> 5) % (ROWS + 2);
        int ic = idx / (32 * (ROWS + 2));
        int yy = y0 + r - 1;
        float f0 = 0.f, f1 = 0.f, f2 = 0.f, f3 = 0.f;
        if (yy >= 0 && yy < HH) {
            ushort4 u = *reinterpret_cast<const ushort4*>(
                &inb[(long long)(g * GIN + ic) * NPIX + yy * WW + seg * 4]);
            f0 = b2f(u.x); f1 = b2f(u.y); f2 = b2f(u.z); f3 = b2f(u.w);
        }
        float* dst = &xs[ic][r][seg * 4 + 1];
        dst[0] = f0; dst[1] = f1; dst[2] = f2; dst[3] = f3;
    }
    for (int idx = tid; idx < GIN * (ROWS + 2); idx += 256) {
        int r = idx % (ROWS + 2), ic = idx / (ROWS + 2);
        xs[ic][r][0] = 0.f;
        xs[ic][r][129] = 0.f;
    }
    __syncthreads();

    constexpr int NOUT2 = GOUT * ROWS * 64;  // ushort2 outputs
    for (int e = tid; e < NOUT2; e += 256) {
        int px2 = (e & 63) * 2;
        int comb = e >> 6;
        int ry = comb % ROWS;
        int oc = comb / ROWS;
        int ocg = g * GOUT + oc;
        const float* wp = Wm + (long long)ocg * GIN * 9;
        float acc0 = bias[ocg];
        float acc1 = acc0;
#pragma unroll
        for (int ic = 0; ic < GIN; ++ic)
#pragma unroll
            for (int ky = 0; ky < 3; ++ky)
#pragma unroll
                for (int kx = 0; kx < 3; ++kx) {
                    float wv = wp[ic * 9 + ky * 3 + kx];
                    acc0 = fmaf(wv, xs[ic][ry + ky][px2 + kx], acc0);
                    acc1 = fmaf(wv, xs[ic][ry + ky][px2 + 1 + kx], acc1);
                }
        ushort2 st;
        st.x = bfbits(acc0);
        st.y = bfbits(acc1);
        *reinterpret_cast<ushort2*>(
            &out[(long long)b * bsout + (long long)ocg * NPIX + (y0 + ry) * WW + px2]) = st;
    }
}

// ---------------------------------------------------------------------------
// NCHW fp32 -> NHWC bf16 transpose-convert (B operand of the MFMA conv).
// ---------------------------------------------------------------------------
__global__ __launch_bounds__(256) void nchw2nhwc_kernel(
    const float* __restrict__ in, unsigned short* __restrict__ outp)
{
    __shared__ float xs[192][65];
    int tid = threadIdx.x;
    int y = blockIdx.x >> 1;
    int x0 = (blockIdx.x & 1) * 64;
    int b = blockIdx.z;

    for (int idx = tid; idx < 192 * 64; idx += 256) {
        int ic = idx >> 6, px = idx & 63;
        xs[ic][px] = in[(((long long)b * CDIM + ic) << 14) + y * WW + x0 + px];
    }
    __syncthreads();
    for (int idx = tid; idx < 64 * 24; idx += 256) {
        int px = idx / 24, grp = idx % 24;
        union { unsigned short u[8]; uint4 v; } pk;
#pragma unroll
        for (int j = 0; j < 8; ++j) pk.u[j] = bfbits(xs[grp * 8 + j][px]);
        *reinterpret_cast<uint4*>(
            &outp[(((long long)b * HH + y) * WW + x0 + px) * CDIM + grp * 8]) = pk.v;
    }
}

// ---------------------------------------------------------------------------
// Pack kv_w (OIHW fp32) -> Wpack[oc][tap][ic] bf16.
// ---------------------------------------------------------------------------
__global__ __launch_bounds__(256) void pack_w_kernel(
    const float* __restrict__ w, unsigned short* __restrict__ wp)
{
    int idx = blockIdx.x * 256 + threadIdx.x;
    if (idx >= 384 * 9 * 192) return;
    int ic = idx % 192;
    int tap = (idx / 192) % 9;
    int oc = idx / (192 * 9);
    wp[idx] = bfbits(w[((long long)oc * 192 + ic) * 9 + tap]);
}

// ---------------------------------------------------------------------------
// Generic fp32 -> bf16 bit convert.
// ---------------------------------------------------------------------------
__global__ __launch_bounds__(256) void cvt_bf16_kernel(
    const float* __restrict__ src, unsigned short* __restrict__ dst, int n)
{
    int i = blockIdx.x * 256 + threadIdx.x;
    if (i < n) dst[i] = bfbits(src[i]);
}

// ---------------------------------------------------------------------------
// Dense 3x3 conv 192->384 via MFMA implicit GEMM.
// K chunked 3x64 ic; LDS xs[3][130][64] u16 (49.9 KB -> 3 blocks/CU).
// XOR swizzle: 16B slot s (= ic/8 within chunk, 0..7) stored at s^(col&7).
// Col stride = 128 B (bank-aligned); swizzle spreads 8 slots over all 32
// banks -> ds_read_b128 ~2-way (free), staging writes at throughput floor.
// ---------------------------------------------------------------------------
__global__ __launch_bounds__(256) void conv3x3_mfma_kernel(
    const unsigned short* __restrict__ Xbf,
    const unsigned short* __restrict__ Wpack,
    const float* __restrict__ bias,
    bf16* __restrict__ out)
{
    __shared__ unsigned short xs[3][130][64];
    int tid = threadIdx.x;
    int lane = tid & 63;
    int wave = tid >> 6;
    int w_oc = wave >> 1;
    int w_px = wave & 1;
    int l15 = lane & 15;
    int lk = lane >> 4;

    int y = blockIdx.x;
    int ocb = blockIdx.y * 64;
    int b = blockIdx.z;
    int ocw = ocb + w_oc * 32;

    f32x4 acc[2][4];
#pragma unroll
    for (int mi = 0; mi < 2; ++mi) {
#pragma unroll
        for (int r = 0; r < 4; ++r) {
            float bz = bias[ocw + mi * 16 + lk * 4 + r];
#pragma unroll
            for (int nf = 0; nf < 4; ++nf) acc[mi][nf][r] = bz;
        }
    }

    for (int chunk = 0; chunk < 3; ++chunk) {
        int ic0 = chunk * 64;
        __syncthreads();
        // stage [3 rows][130 cols][64 ic] bf16, 16 B per thread-iter, swizzled
        for (int idx = tid; idx < 3 * 130 * 8; idx += 256) {
            int grp = idx & 7;
            int col = (idx >> 3) % 130;
            int ky = idx / (8 * 130);
            int yy = y + ky - 1;
            int xx = col - 1;
            uint4 val = make_uint4(0u, 0u, 0u, 0u);
            if (yy >= 0 && yy < HH && xx >= 0 && xx < WW)
                val = *reinterpret_cast<const uint4*>(
                    &Xbf[(((long long)b * HH + yy) * WW + xx) * CDIM + ic0 + grp * 8]);
            int slot = grp ^ (col & 7);
            *reinterpret_cast<uint4*>(&xs[ky][col][slot * 8]) = val;
        }
        __syncthreads();

#pragma unroll
        for (int tap = 0; tap < 9; ++tap) {
            int ky = tap / 3, kx = tap % 3;
#pragma unroll
            for (int ks = 0; ks < 2; ++ks) {
                bf16x8 a[2];
#pragma unroll
                for (int mi = 0; mi < 2; ++mi) {
                    int oc = ocw + mi * 16 + l15;
                    a[mi] = *reinterpret_cast<const bf16x8*>(
                        &Wpack[(((long long)oc * 9 + tap) * CDIM) + ic0 + ks * 32 + lk * 8]);
                }
                bf16x8 bv[4];
#pragma unroll
                for (int nf = 0; nf < 4; ++nf) {
                    int col = w_px * 64 + nf * 16 + l15 + kx;
                    int slot = (ks * 4 + lk) ^ (col & 7);
                    bv[nf] = *reinterpret_cast<const bf16x8*>(&xs[ky][col][slot * 8]);
                }
#pragma unroll
                for (int mi = 0; mi < 2; ++mi)
#pragma unroll
                    for (int nf = 0; nf < 4; ++nf)
                        acc[mi][nf] = __builtin_amdgcn_mfma_f32_16x16x32_bf16(
                            a[mi], bv[nf], acc[mi][nf], 0, 0, 0);
            }
        }
    }

#pragma unroll
    for (int mi = 0; mi < 2; ++mi) {
#pragma unroll
        for (int nf = 0; nf < 4; ++nf) {
            int x = w_px * 64 + nf * 16 + l15;
#pragma unroll
            for (int r = 0; r < 4; ++r) {
                int oc = ocw + mi * 16 + lk * 4 + r;
                stF(&out[(((long long)b * 384 + oc) << 14) + y * WW + x], acc[mi][nf][r]);
            }
        }
    }
}

// ---------------------------------------------------------------------------
// Reductions: per-channel sumsq q,k,v + 24x24 Gram(q,k). (unchanged)
// ---------------------------------------------------------------------------
__global__ __launch_bounds__(256) void reduce_qkv_kernel(
    const bf16* __restrict__ q, long long bsq,
    const bf16* __restrict__ k, long long bsk,
    const bf16* __restrict__ v, long long bsv,
    float* __restrict__ ssq, float* __restrict__ gram)
{
    __shared__ float qs[24][129], ks[24][129], vs[24][129];
    int bh = blockIdx.x;
    int b = bh >> 3, h = bh & 7;
    int n0 = blockIdx.y * 256;
    int tid = threadIdx.x;

    float ag0 = 0.f, ag1 = 0.f, ag2 = 0.f;
    float accs = 0.f;
    int e0 = tid, e1 = tid + 256, e2 = tid + 512;

    for (int cc = 0; cc < 2; ++cc) {
        int nb = n0 + cc * 128;
        __syncthreads();
        for (int idx = tid; idx < 24 * 128; idx += 256) {
            int c = idx >> 7, i = idx & 127;
            long long off = (long long)(h * CP + c) * NPIX + nb + i;
            qs[c][i] = toF(q[(long long)b * bsq + off]);
            ks[c][i] = toF(k[(long long)b * bsk + off]);
            vs[c][i] = toF(v[(long long)b * bsv + off]);
        }
        __syncthreads();
        {
            int cq = e0 / 24, ck = e0 % 24;
            for (int i = 0; i < 128; ++i) ag0 = fmaf(qs[cq][i], ks[ck][i], ag0);
        }
        {
            int cq = e1 / 24, ck = e1 % 24;
            for (int i = 0; i < 128; ++i) ag1 = fmaf(qs[cq][i], ks[ck][i], ag1);
        }
        if (tid < 64) {
            int cq = e2 / 24, ck = e2 % 24;
            for (int i = 0; i < 128; ++i) ag2 = fmaf(qs[cq][i], ks[ck][i], ag2);
        }
        if (tid < 72) {
            int tensor = tid / 24, c = tid % 24;
            const float (*src)[129] = (tensor == 0) ? qs : (tensor == 1) ? ks : vs;
            for (int i = 0; i < 128; ++i) accs = fmaf(src[c][i], src[c][i], accs);
        }
    }
    float* gb = gram + (long long)bh * 576;
    atomicAdd(&gb[e0], ag0);
    atomicAdd(&gb[e1], ag1);
    if (tid < 64) atomicAdd(&gb[e2], ag2);
    if (tid < 72) {
        int tensor = tid / 24, c = tid % 24;
        atomicAdd(&ssq[tensor * (NB * CDIM) + b * CDIM + h * CP + c], accs);
    }
}

// ---------------------------------------------------------------------------
// Softmax + fold norms + proj into per-batch M (192x192), output bf16.
// ---------------------------------------------------------------------------
__global__ __launch_bounds__(256) void build_M_kernel(
    const float* __restrict__ ssq, const float* __restrict__ gram,
    const float* __restrict__ temp, const float* __restrict__ proj_w,
    unsigned short* __restrict__ Mout)
{
    __shared__ float A[HEADS][CP][CP];
    __shared__ float nq[CDIM], nk[CDIM], nv[CDIM];
    int b = blockIdx.x;
    int tid = threadIdx.x;
    if (tid < CDIM) {
        nq[tid] = fmaxf(sqrtf(ssq[0 * (NB * CDIM) + b * CDIM + tid]), 1e-12f);
        nk[tid] = fmaxf(sqrtf(ssq[1 * (NB * CDIM) + b * CDIM + tid]), 1e-12f);
        nv[tid] = fmaxf(sqrtf(ssq[2 * (NB * CDIM) + b * CDIM + tid]), 1e-12f);
    }
    __syncthreads();
    if (tid < CDIM) {
        int h = tid / CP, cq = tid % CP;
        float t = temp[h];
        float row[CP];
        float m = -1e30f;
#pragma unroll
        for (int ck = 0; ck < CP; ++ck) {
            float g = gram[(long long)b * (HEADS * 576) + h * 576 + cq * CP + ck];
            g = g / (nq[h * CP + cq] * nk[h * CP + ck]) * t;
            row[ck] = g;
            m = fmaxf(m, g);
        }
        float s = 0.f;
#pragma unroll
        for (int ck = 0; ck < CP; ++ck) { row[ck] = __expf(row[ck] - m); s += row[ck]; }
        float inv = 1.f / s;
#pragma unroll
        for (int ck = 0; ck < CP; ++ck)
            A[h][cq][ck] = row[ck] * inv / nv[h * CP + ck];
    }
    __syncthreads();
    for (int e = tid; e < CDIM * CDIM; e += 256) {
        int oc = e / CDIM, d = e % CDIM;
        int h2 = d / CP, ck = d % CP;
        float acc = 0.f;
#pragma unroll
        for (int cq = 0; cq < CP; ++cq)
            acc = fmaf(proj_w[(long long)oc * CDIM + h2 * CP + cq], A[h2][cq][ck], acc);
        Mout[(long long)b * (CDIM * CDIM) + e] = bfbits(acc);
    }
}

__global__ void zero_kernel(float* __restrict__ p, int n)
{
    for (int i = blockIdx.x * 256 + threadIdx.x; i < n; i += gridDim.x * 256) p[i] = 0.f;
}

// ---------------------------------------------------------------------------
// Workspace layout (u16 element offsets unless noted), total < 202 MB:
//   A u16[37,748,736] @ 0 B:
//     S1 qkv1 (full) -> S3 kv1 [0:25,165,824) -> k_new [0:12,582,912),
//     v_new [12,582,912:25,165,824)
//     tail (free after S2): nkb @25,165,824, nvb @25,239,552, Mbf @25,313,280
//   B u16[37,748,736] @ 75,497,472 B:  qwb [0:110,592) (pre-S1) -> S2 qkv
//   C u16[25,165,824] @ 150,994,944 B: Wpack [0:663,552),
//     Xbf [663,552:13,246,464) -> S4 kv2 (full)
//   stats f32 @ 201,326,592 B: ssq 2304 | gram 18432
// ---------------------------------------------------------------------------
extern "C" void kernel_launch(void* const* d_in, const int* in_sizes, int n_in,
                              void* d_out, int out_size, void* d_ws, size_t ws_size,
                              hipStream_t stream)
{
    const float* x      = (const float*)d_in[0];
    const float* x_mask = (const float*)d_in[1];
    const float* temp   = (const float*)d_in[2];
    const float* q_w    = (const float*)d_in[3];
    const float* q_b    = (const float*)d_in[4];
    const float* qdw_w  = (const float*)d_in[5];
    const float* qdw_b  = (const float*)d_in[6];
    const float* kv_w   = (const float*)d_in[7];
    const float* kv_b   = (const float*)d_in[8];
    const float* kvdw_w = (const float*)d_in[9];
    const float* kvdw_b = (const float*)d_in[10];
    const float* newk_w = (const float*)d_in[11];
    const float* newk_b = (const float*)d_in[12];
    const float* newv_w = (const float*)d_in[13];
    const float* newv_b = (const float*)d_in[14];
    const float* proj_w = (const float*)d_in[15];
    const float* proj_b = (const float*)d_in[16];

    char* wsb = (char*)d_ws;
    bf16* A  = (bf16*)wsb;
    bf16* Bq = (bf16*)(wsb + 75497472);
    bf16* C  = (bf16*)(wsb + 150994944);
    unsigned short* qwb   = (unsigned short*)Bq;                    // 110,592
    unsigned short* nkb   = (unsigned short*)A + 25165824;          // 73,728
    unsigned short* nvb   = (unsigned short*)A + 25239552;          // 73,728
    unsigned short* Mbf   = (unsigned short*)A + 25313280;          // 147,456
    unsigned short* Wpack = (unsigned short*)C;                     // 663,552
    unsigned short* Xbf   = (unsigned short*)C + 663552;            // 12,582,912
    float* stats = (float*)(wsb + 201326592);
    float* ssq  = stats;                                            // 2304
    float* gram = ssq + 2304;                                       // 18432

    const long long N = NPIX;
    float* out = (float*)d_out;

    // stats zero + weight packs needed before S1
    zero_kernel<<<16, 256, 0, stream>>>(ssq, 2304 + 18432);
    cvt_bf16_kernel<<<432, 256, 0, stream>>>(q_w, qwb, 576 * 192);
    pack_w_kernel<<<(384 * 9 * 192 + 255) / 256, 256, 0, stream>>>(kv_w, Wpack);

    // S1: qkv1 = conv1x1(x, q_w) : 192 -> 576 (fp32 in, bf16 out) -> A
    gemm1x1_mfma_kernel<float, bf16><<<dim3(128, 9, 4), 256, 0, stream>>>(
        x, 192 * N, x, 0, 192, 192, qwb, 0, q_b, A, 576 * N);

    // S2: qkv = grouped 3x3 (groups=192, 3in/3out) -> B
    dwconv3x3_kernel<3, 3, 8><<<dim3(16, 192, 4), 256, 0, stream>>>(
        A, qdw_w, qdw_b, Bq, 192);

    // packs into A-tail (A dead after S2) + NHWC convert into C
    cvt_bf16_kernel<<<288, 256, 0, stream>>>(newk_w, nkb, 192 * 384);
    cvt_bf16_kernel<<<288, 256, 0, stream>>>(newv_w, nvb, 192 * 384);
    nchw2nhwc_kernel<<<dim3(256, 1, 4), 256, 0, stream>>>(x_mask, Xbf);

    // S3: kv1 = dense conv3x3(x_mask) 192->384 via MFMA -> A[0:25.17M)
    conv3x3_mfma_kernel<<<dim3(128, 6, 4), 256, 0, stream>>>(Xbf, Wpack, kv_b, A);

    // S4: kv2 = depthwise 3x3 (384 groups) -> C (overwrites Wpack/Xbf, done)
    dwconv3x3_kernel<1, 1, 16><<<dim3(8, 384, 4), 256, 0, stream>>>(
        A, kvdw_w, kvdw_b, C, 384);

    // S5: k_new / v_new = conv1x1 of concat, MFMA -> A[0:25.17M)
    bf16* k_new = A;
    bf16* v_new = A + 12582912;
    gemm1x1_mfma_kernel<bf16, bf16><<<dim3(128, 3, 4), 256, 0, stream>>>(
        Bq + 192 * N, 576 * N, C, 384 * N, 192, 384, nkb, 0, newk_b,
        k_new, 192 * N);
    gemm1x1_mfma_kernel<bf16, bf16><<<dim3(128, 3, 4), 256, 0, stream>>>(
        Bq + 384 * N, 576 * N, C + 192 * N, 384 * N, 192, 384, nvb, 0, newv_b,
        v_new, 192 * N);

    // S6: sumsq(q,k,v) + Gram(q,k)
    reduce_qkv_kernel<<<dim3(32, 64), 256, 0, stream>>>(
        Bq, 576 * N, k_new, 192 * N, v_new, 192 * N, ssq, gram);

    // S7: softmax + fold v-norm + proj -> per-batch M (bf16)
    build_M_kernel<<<4, 256, 0, stream>>>(ssq, gram, temp, proj_w, Mbf);

    // S8: out = M_b @ v_new + proj_b (bf16 in, fp32 out)
    gemm1x1_mfma_kernel<bf16, float><<<dim3(128, 3, 4), 256, 0, stream>>>(
        v_new, 192 * N, v_new, 0, 192, 192, Mbf, (long long)CDIM * CDIM,
        proj_b, out, 192 * N);
}